// Round 6
// baseline (17.249 us; speedup 1.0000x reference)
//
#include <hip/hip_runtime.h>

#define NG 256        // number of graphs
#define NBLK 2048     // total blocks (8 per CU), uniform flat edge split

typedef int int4v __attribute__((ext_vector_type(4)));

// ---------------------------------------------------------------------------
// Flat, quad-per-thread. Every block:
//   1. shfl-based inclusive scan of (n, epg) over 256 graphs (2 barriers).
//   2. covers global edge ranks [blk*W, blk*W+W); thread t emits the FOUR
//      consecutive edges starting at k = blk*W + 4t each iteration, as two
//      16B stores (32B/lane; the two back-to-back store instrs fully tile
//      each 128B line, merged in L2). One rcp-division per quad; edges 2-4
//      derived by +1 wrap-advances. Pairs never straddle a graph (all epg
//      even); the second pair re-resolves its graph when it crosses.
// ---------------------------------------------------------------------------
__global__ __launch_bounds__(256) void fc_quad_kernel(
    const int* __restrict__ num_nodes,
    int* __restrict__ d_out, int e2 /* = 2*E */, int W /* edges/block, %256==0 */) {
    __shared__ int s_in[NG + 1];  // cumsum of n,   s_in[0] = 0
    __shared__ int s_ie[NG + 1];  // cumsum of epg, s_ie[0] = 0
    __shared__ int wsum_n[4], wsum_e[4];

    const int t = threadIdx.x;
    const int lane = t & 63;
    const int w = t >> 6;

    const int n0 = num_nodes[t];
    const int d0 = (n0 > 1) ? (n0 - 1) : 0;
    const int e0 = n0 * d0;

    int sn = n0, se = e0;
    #pragma unroll
    for (int off = 1; off < 64; off <<= 1) {
        const int an = __shfl_up(sn, off);
        const int ae = __shfl_up(se, off);
        if (lane >= off) { sn += an; se += ae; }
    }
    if (lane == 63) { wsum_n[w] = sn; wsum_e[w] = se; }
    __syncthreads();
    #pragma unroll
    for (int w2 = 0; w2 < 3; ++w2)
        if (w > w2) { sn += wsum_n[w2]; se += wsum_e[w2]; }
    s_in[t + 1] = sn;
    s_ie[t + 1] = se;
    if (t == 0) { s_in[0] = 0; s_ie[0] = 0; }

    // Second tuple output: num_edges per graph.
    if (blockIdx.x == 0) d_out[e2 + t] = e0;
    __syncthreads();

    const int E = e2 >> 1;
    int k = blockIdx.x * W + 4 * t;            // first edge of this thread's quad
    const int kend = min(blockIdx.x * W + W, E);
    if (k >= kend) return;

    int lo = 0, hi = NG;
    #pragma unroll
    for (int step = 0; step < 8; ++step) {
        const int mid = (lo + hi) >> 1;
        if (k >= s_ie[mid]) lo = mid; else hi = mid;
    }
    int g = lo;
    int e_hi = s_ie[g + 1];

    int4v* out4 = reinterpret_cast<int4v*>(d_out);
    for (; k < kend; k += 1024) {              // 256 threads x 4 edges
        while (k >= e_hi) { ++g; e_hi = s_ie[g + 1]; }
        const int base = s_in[g];
        const int deg = (s_in[g + 1] - base) - 1;   // >= 1 where edges exist
        const int kl = k - s_ie[g];
        // pair A: edges k, k+1
        int i = (int)((float)kl * __builtin_amdgcn_rcpf((float)deg));
        int r = kl - i * deg;
        if (r < 0)         { --i; r += deg; }
        else if (r >= deg) { ++i; r -= deg; }
        const int j0 = r + ((r >= i) ? 1 : 0);
        int i1 = i, r1 = r + 1;
        if (r1 == deg) { r1 = 0; ++i1; }
        const int j1 = r1 + ((r1 >= i1) ? 1 : 0);
        int4v vA;
        vA.x = base + i;  vA.y = base + j0;
        vA.z = base + i1; vA.w = base + j1;
        out4[k >> 1] = vA;

        // pair B: edges k+2, k+3 (guarded: may cross a graph or the range end)
        const int kB = k + 2;
        if (kB < kend) {
            int baseB = base, degB = deg, i2, r2;
            if (kB >= e_hi) {
                while (kB >= e_hi) { ++g; e_hi = s_ie[g + 1]; }
                baseB = s_in[g];
                degB = (s_in[g + 1] - baseB) - 1;
                i2 = 0; r2 = 0;                 // kl == 0 in the new graph
            } else {
                i2 = i; r2 = r + 2;
                if (r2 >= deg) { r2 -= deg; ++i2; }  // deg>=2 here: at most once
            }
            const int j2 = r2 + ((r2 >= i2) ? 1 : 0);
            int i3 = i2, r3 = r2 + 1;
            if (r3 == degB) { r3 = 0; ++i3; }
            const int j3 = r3 + ((r3 >= i3) ? 1 : 0);
            int4v vB;
            vB.x = baseB + i2; vB.y = baseB + j2;
            vB.z = baseB + i3; vB.w = baseB + j3;
            out4[(k >> 1) + 1] = vB;
        }
    }
}

extern "C" void kernel_launch(void* const* d_in, const int* in_sizes, int n_in,
                              void* d_out, int out_size, void* d_ws, size_t ws_size,
                              hipStream_t stream) {
    const int* num_nodes = (const int*)d_in[0];  // [256] int32
    int* out = (int*)d_out;                      // [2E + 256] int32
    const int e2 = out_size - NG;                // 2*E
    const int E = e2 / 2;                        // even (sum of n*(n-1))

    // Edges per block: uniform, rounded to 256 (quad- and wave-aligned).
    int W = (E + NBLK - 1) / NBLK;
    W = (W + 255) & ~255;

    fc_quad_kernel<<<NBLK, 256, 0, stream>>>(num_nodes, out, e2, W);
}

// Round 7
// 14.034 us; speedup vs baseline: 1.2290x; 1.2290x over previous
//
#include <hip/hip_runtime.h>

#define NG 256        // number of graphs
#define NBLK 2048     // total blocks (8 per CU), uniform flat edge split

typedef int int4v __attribute__((ext_vector_type(4)));  // clang vector: valid
                                                        // for nontemporal store

// ---------------------------------------------------------------------------
// Flat, pairwise. Every block:
//   1. shfl-based inclusive scan of (n, epg) over 256 graphs (2 barriers).
//   2. handles contiguous global edge ranks [k0, k0+W); each thread emits
//      TWO consecutive edges per iteration as one 16B nontemporal store
//      (full 1KB/wave-store). Both epg and E are even, and all cumsum
//      boundaries are even, so an even-k pair never straddles a graph.
//      One rcp-division per pair; the second edge is a +1 wrap fixup.
// R6 post-mortem: 4-edge/thread variant (32B/lane, two strided 16B stores,
// no NT) regressed 14.0 -> 17.2 us — store-instruction density + NT is the
// binding constraint, not VALU. This dense-1KB-per-wave-store layout is the
// same shape as the harness fill kernel that demonstrates 6.1 TB/s.
// ---------------------------------------------------------------------------
__global__ __launch_bounds__(256) void fc_pair_kernel(
    const int* __restrict__ num_nodes,
    int* __restrict__ d_out, int e2 /* = 2*E */, int W /* edges/block, even */) {
    __shared__ int s_in[NG + 1];  // cumsum of n,   s_in[0] = 0
    __shared__ int s_ie[NG + 1];  // cumsum of epg, s_ie[0] = 0
    __shared__ int wsum_n[4], wsum_e[4];

    const int t = threadIdx.x;
    const int lane = t & 63;
    const int w = t >> 6;

    const int n0 = num_nodes[t];
    const int d0 = (n0 > 1) ? (n0 - 1) : 0;
    const int e0 = n0 * d0;

    int sn = n0, se = e0;
    #pragma unroll
    for (int off = 1; off < 64; off <<= 1) {
        const int an = __shfl_up(sn, off);
        const int ae = __shfl_up(se, off);
        if (lane >= off) { sn += an; se += ae; }
    }
    if (lane == 63) { wsum_n[w] = sn; wsum_e[w] = se; }
    __syncthreads();
    #pragma unroll
    for (int w2 = 0; w2 < 3; ++w2)
        if (w > w2) { sn += wsum_n[w2]; se += wsum_e[w2]; }
    s_in[t + 1] = sn;
    s_ie[t + 1] = se;
    if (t == 0) { s_in[0] = 0; s_ie[0] = 0; }

    // Second tuple output: num_edges per graph.
    if (blockIdx.x == 0) d_out[e2 + t] = e0;
    __syncthreads();

    // --- this thread's pair range ---
    const int E = e2 >> 1;
    int k = blockIdx.x * W + 2 * t;            // even: first edge of the pair
    const int kend = min(blockIdx.x * W + W, E);
    if (k >= kend) return;

    int lo = 0, hi = NG;
    #pragma unroll
    for (int step = 0; step < 8; ++step) {
        const int mid = (lo + hi) >> 1;
        if (k >= s_ie[mid]) lo = mid; else hi = mid;
    }
    int g = lo;
    int e_hi = s_ie[g + 1];

    int4v* out4 = reinterpret_cast<int4v*>(d_out);
    for (; k < kend; k += 512) {               // 256 threads x 2 edges
        while (k >= e_hi) { ++g; e_hi = s_ie[g + 1]; }
        const int base = s_in[g];
        const int deg = (s_in[g + 1] - base) - 1;   // >= 1 where edges exist
        const int kl = k - s_ie[g];
        int i = (int)((float)kl * __builtin_amdgcn_rcpf((float)deg));
        int r = kl - i * deg;
        if (r < 0)         { --i; r += deg; }
        else if (r >= deg) { ++i; r -= deg; }
        const int j1 = r + ((r >= i) ? 1 : 0);
        int i2 = i, r2 = r + 1;
        if (r2 == deg) { r2 = 0; ++i2; }            // wrap to next row
        const int j2 = r2 + ((r2 >= i2) ? 1 : 0);
        int4v v;
        v.x = base + i;  v.y = base + j1;
        v.z = base + i2; v.w = base + j2;
        __builtin_nontemporal_store(v, &out4[k >> 1]);
    }
}

extern "C" void kernel_launch(void* const* d_in, const int* in_sizes, int n_in,
                              void* d_out, int out_size, void* d_ws, size_t ws_size,
                              hipStream_t stream) {
    const int* num_nodes = (const int*)d_in[0];  // [256] int32
    int* out = (int*)d_out;                      // [2E + 256] int32
    const int e2 = out_size - NG;                // 2*E
    const int E = e2 / 2;                        // E is even (sum of n*(n-1))

    // Edges per block: uniform, rounded to 128 edges (pair- and wave-aligned).
    int W = (E + NBLK - 1) / NBLK;
    W = (W + 127) & ~127;

    fc_pair_kernel<<<NBLK, 256, 0, stream>>>(num_nodes, out, e2, W);
}